// Round 9
// baseline (75.206 us; speedup 1.0000x reference)
//
#include <hip/hip_runtime.h>
#include <math.h>

#define NROW 768
#define DIM  128

constexpr int H0c  = 256;
constexpr int H1c  = 362;
constexpr int HP1c = 368;   // H1 padded; pad columns are exact zeros

// Workspace layout (float offsets). ~3.9 MB total.
// hx stored in PANEL layout: [HP/4][768][4] so the pair kernel's per-thread
// read hx[i, hb..hb+3] is one coalesced float4 (lane = i).
constexpr int HX0_OFF  = 0;         // [64][768][4]
constexpr int HYB0_OFF = 196608;    // [768][256]   hy0 + b1_0 (row-major)
constexpr int HX1_OFF  = 393216;    // [92][768][4]
constexpr int HYB1_OFF = 675840;    // [768][368]   hy1 + b1_1 (row-major)
constexpr int PMAX_OFF = 958464;    // [2][768][4]  per-iq row max (slots 0..2)
constexpr int PSUM_OFF = 964608;    // [2][768][4]
constexpr int DIAG_OFF = 970752;    // [2][768]     s_diag
constexpr int UHP_OFF  = 972288;    // [2][2][768]  u partials (est, ht)
constexpr int W2P_OFF  = 975360;    // [2][368]     zero-padded W2 copies

// ---------------------------------------------------------------------------
// prep: four projections (256 thr, 4h x 4rows, 16 fma chains / thread).
// (structure unchanged from round 8 — passing)
// ---------------------------------------------------------------------------
template <int M, int HT>
__device__ __forceinline__ void prep_body(
    const float* __restrict__ s0, const float* __restrict__ s1, const float* __restrict__ s2,
    const float* __restrict__ W1_0, const float* __restrict__ b1_0, const float* __restrict__ W2_0,
    const float* __restrict__ W1_1, const float* __restrict__ b1_1, const float* __restrict__ W2_1,
    float* __restrict__ ws, float* __restrict__ xs) {
  constexpr int K     = (M == 2) ? 256 : 128;
  constexpr int HREAL = (M <= 1) ? H0c : H1c;
  constexpr int HP    = (M <= 1) ? H0c : HP1c;
  constexpr int WOFF  = (M == 1) ? 128 : (M == 3) ? 256 : 0;
  constexpr int HACT  = (M <= 1) ? 256 : 184;
  constexpr int EST   = (M <= 1) ? 0 : 1;

  const float* __restrict__ W    = (M <= 1) ? W1_0 : W1_1;
  const float* __restrict__ bias = (M == 1) ? b1_0 : (M == 3) ? b1_1 : nullptr;
  const float* __restrict__ W2   = (M <= 1) ? W2_0 : W2_1;

  const int i0  = blockIdx.x * 16;
  const int tx  = threadIdx.x;            // 0..63
  const int ty  = threadIdx.y;            // 0..3
  const int tid = ty * 64 + tx;

  {
    const float* __restrict__ sa = (M == 3) ? s2 : (M == 1) ? s1 : s0;
    constexpr int NF4 = 16 * (K / 4);
    for (int idx = tid; idx < NF4; idx += 256) {
      const int row = idx / (K / 4);
      const int c4  = (idx % (K / 4)) * 4;
      float4 v;
      if (M == 2 && c4 >= DIM)
        v = *(const float4*)&s1[(i0 + row) * DIM + (c4 - DIM)];
      else
        v = *(const float4*)&sa[(i0 + row) * DIM + c4];
      *(float4*)&xs[row * K + c4] = v;
    }
  }
  __syncthreads();

  const bool own   = (tx * 4 < HACT);
  const int  h4    = HT * HACT + tx * 4;
  const bool fullw = (h4 + 4 <= HREAL);
  const int  h4c   = fullw ? h4 : (HREAL - 4);
  const int  r0    = ty * 4;
  float acc[4][4] = {};
  const float* __restrict__ Wb = W + WOFF * HREAL + h4c;

  for (int d = 0; d < K; d += 4) {
    float4 xv[4];
    #pragma unroll
    for (int r = 0; r < 4; ++r) xv[r] = *(const float4*)&xs[(r0 + r) * K + d];
    float4 wv[4];
    #pragma unroll
    for (int dd = 0; dd < 4; ++dd)
      wv[dd] = *(const float4*)&Wb[(d + dd) * HREAL];
    #pragma unroll
    for (int dd = 0; dd < 4; ++dd) {
      #pragma unroll
      for (int r = 0; r < 4; ++r) {
        const float xval = ((const float*)&xv[r])[dd];
        acc[r][0] = fmaf(xval, wv[dd].x, acc[r][0]);
        acc[r][1] = fmaf(xval, wv[dd].y, acc[r][1]);
        acc[r][2] = fmaf(xval, wv[dd].z, acc[r][2]);
        acc[r][3] = fmaf(xval, wv[dd].w, acc[r][3]);
      }
    }
  }

  if (M >= 2 && !fullw && h4 < HREAL) {
    #pragma unroll
    for (int r = 0; r < 4; ++r) {
      acc[r][0] = acc[r][2]; acc[r][1] = acc[r][3];
      acc[r][2] = 0.f;       acc[r][3] = 0.f;
    }
  }

  const bool ok0 = (h4 + 0 < HREAL), ok1 = (h4 + 1 < HREAL),
             ok2 = (h4 + 2 < HREAL), ok3 = (h4 + 3 < HREAL);

  float* __restrict__ outp = ws + ((M == 0) ? HX0_OFF : (M == 1) ? HYB0_OFF
                                 : (M == 2) ? HX1_OFF : HYB1_OFF);
  if (own && h4 < HP) {
    if ((M & 1) == 0) {
      const int pbase = (h4 >> 2) * (NROW * 4);
      #pragma unroll
      for (int r = 0; r < 4; ++r) {
        float4 v;
        v.x = ok0 ? acc[r][0] : 0.f;
        v.y = ok1 ? acc[r][1] : 0.f;
        v.z = ok2 ? acc[r][2] : 0.f;
        v.w = ok3 ? acc[r][3] : 0.f;
        *(float4*)&outp[pbase + (i0 + r0 + r) * 4] = v;
      }
    } else {
      float bv[4] = {0.f, 0.f, 0.f, 0.f};
      if (ok0) bv[0] = bias[h4 + 0];
      if (ok1) bv[1] = bias[h4 + 1];
      if (ok2) bv[2] = bias[h4 + 2];
      if (ok3) bv[3] = bias[h4 + 3];
      #pragma unroll
      for (int r = 0; r < 4; ++r) {
        float4 v;
        v.x = ok0 ? acc[r][0] + bv[0] : 0.f;
        v.y = ok1 ? acc[r][1] + bv[1] : 0.f;
        v.z = ok2 ? acc[r][2] + bv[2] : 0.f;
        v.w = ok3 ? acc[r][3] + bv[3] : 0.f;
        *(float4*)&outp[(i0 + r0 + r) * HP + h4] = v;
      }
    }
  }

  if ((M & 1) == 0) {
    float w2v[4];
    w2v[0] = (own && ok0) ? W2[h4 + 0] : 0.f;
    w2v[1] = (own && ok1) ? W2[h4 + 1] : 0.f;
    w2v[2] = (own && ok2) ? W2[h4 + 2] : 0.f;
    w2v[3] = (own && ok3) ? W2[h4 + 3] : 0.f;
    #pragma unroll
    for (int r = 0; r < 4; ++r) {
      float p = acc[r][0] * w2v[0] + acc[r][1] * w2v[1] +
                acc[r][2] * w2v[2] + acc[r][3] * w2v[3];
      #pragma unroll
      for (int off = 32; off > 0; off >>= 1) p += __shfl_xor(p, off);
      if (tx == 0)
        ws[UHP_OFF + EST * 1536 + HT * NROW + i0 + r0 + r] = p;
    }
  }
}

__global__ __launch_bounds__(256) void prep_kernel(
    const float* __restrict__ s0, const float* __restrict__ s1, const float* __restrict__ s2,
    const float* __restrict__ W1_0, const float* __restrict__ b1_0, const float* __restrict__ W2_0,
    const float* __restrict__ W1_1, const float* __restrict__ b1_1, const float* __restrict__ W2_1,
    float* __restrict__ ws) {
  __shared__ float xs[16 * 256];
  // one block also writes the zero-padded W2 copies used by pair
  if (blockIdx.y == 0 && blockIdx.x == 0) {
    const int t = threadIdx.y * 64 + threadIdx.x;
    for (int h = t; h < HP1c; h += 256) {
      ws[W2P_OFF + h]        = (h < H0c) ? W2_0[h] : 0.f;
      ws[W2P_OFF + HP1c + h] = (h < H1c) ? W2_1[h] : 0.f;
    }
  }
  switch (blockIdx.y) {
    case 0: prep_body<0, 0>(s0, s1, s2, W1_0, b1_0, W2_0, W1_1, b1_1, W2_1, ws, xs); break;
    case 1: prep_body<1, 0>(s0, s1, s2, W1_0, b1_0, W2_0, W1_1, b1_1, W2_1, ws, xs); break;
    case 2: prep_body<2, 0>(s0, s1, s2, W1_0, b1_0, W2_0, W1_1, b1_1, W2_1, ws, xs); break;
    case 3: prep_body<2, 1>(s0, s1, s2, W1_0, b1_0, W2_0, W1_1, b1_1, W2_1, ws, xs); break;
    case 4: prep_body<3, 0>(s0, s1, s2, W1_0, b1_0, W2_0, W1_1, b1_1, W2_1, ws, xs); break;
    default: prep_body<3, 1>(s0, s1, s2, W1_0, b1_0, W2_0, W1_1, b1_1, W2_1, ws, xs); break;
  }
}

// ---------------------------------------------------------------------------
// pair: round-8 launch shape (256 thr, I=1, 3 iq), but y/w read DIRECTLY from
// global with wave-uniform addresses (scalar-cache / broadcast path — zero DS
// in the main loop), and est work balanced: est1 J=3 (256 tiles, 92 quads),
// est0 J=4 (192 tiles, 64 quads); est1 dispatched first (z=0) so the short
// est0 blocks fill the tail.
//   s[j,i] = 0.5*u_i + 0.5*sum_h w_h*|hx[i,h]+hyb[j,h]|
// 2 VALU/elem: v_add z,(s)y,(v)x ; v_fma acc,|z|,(s)w,acc  (1 SGPR/instr ok).
// ---------------------------------------------------------------------------
template <int HP, int HREAL, int J, bool TWO>
__device__ __forceinline__ void pair_body(
    const float* __restrict__ hx4, const float* __restrict__ hyb,
    const float* __restrict__ w2p, const float* __restrict__ uhp,
    float* __restrict__ pmax, float* __restrict__ psum, float* __restrict__ sdiag,
    float* redm, float* reds) {
  const int tid = threadIdx.x;          // 0..255
  const int j0  = blockIdx.x * J;
  const int iq  = blockIdx.y;           // 0..2
  const int i   = iq * 256 + tid;

  float u = uhp[i];
  if (TWO) u += uhp[NROW + i];
  u *= 0.5f;

  float acc[J];
  #pragma unroll
  for (int r = 0; r < J; ++r) acc[r] = 0.f;

  const float* __restrict__ xp = hx4 + i * 4;
  const float* __restrict__ yr[J];
  #pragma unroll
  for (int r = 0; r < J; ++r) yr[r] = hyb + (j0 + r) * HP;

  #pragma unroll 4
  for (int hb = 0; hb < HP; hb += 4, xp += NROW * 4) {
    const float4 a = *(const float4*)xp;                 // per-lane (VMEM)
    const float4 w = *(const float4*)&w2p[hb];           // uniform
    #pragma unroll
    for (int r = 0; r < J; ++r) {
      const float4 y = *(const float4*)&yr[r][hb];       // uniform
      acc[r] = fmaf(fabsf(a.x + y.x), w.x, acc[r]);
      acc[r] = fmaf(fabsf(a.y + y.y), w.y, acc[r]);
      acc[r] = fmaf(fabsf(a.z + y.z), w.z, acc[r]);
      acc[r] = fmaf(fabsf(a.w + y.w), w.w, acc[r]);
    }
  }

  float s[J];
  #pragma unroll
  for (int r = 0; r < J; ++r) s[r] = fmaf(0.5f, acc[r], u);

  // diagonal s (t0 path; v_j and b2 cancel against lse)
  const int dj = i - j0;
  #pragma unroll
  for (int r = 0; r < J; ++r)
    if (dj == r) sdiag[i] = s[r];

  const int lane = tid & 63;
  const int wv   = tid >> 6;   // 0..3

  float M[J];
  #pragma unroll
  for (int r = 0; r < J; ++r) {
    float mm = s[r];
    #pragma unroll
    for (int off = 32; off > 0; off >>= 1) mm = fmaxf(mm, __shfl_xor(mm, off));
    M[r] = mm;
  }
  if (lane == 0) {
    #pragma unroll
    for (int r = 0; r < J; ++r) redm[wv * J + r] = M[r];
  }
  __syncthreads();
  #pragma unroll
  for (int r = 0; r < J; ++r)
    M[r] = fmaxf(fmaxf(redm[r], redm[J + r]), fmaxf(redm[2 * J + r], redm[3 * J + r]));

  #pragma unroll
  for (int r = 0; r < J; ++r) {
    float e = __expf(s[r] - M[r]);
    #pragma unroll
    for (int off = 32; off > 0; off >>= 1) e += __shfl_xor(e, off);
    if (lane == 0) reds[wv * J + r] = e;
  }
  __syncthreads();
  if (tid < J) {
    const float m = fmaxf(fmaxf(redm[tid], redm[J + tid]),
                          fmaxf(redm[2 * J + tid], redm[3 * J + tid]));
    const float sm = reds[tid] + reds[J + tid] + reds[2 * J + tid] + reds[3 * J + tid];
    pmax[(j0 + tid) * 4 + iq] = m;
    psum[(j0 + tid) * 4 + iq] = sm;
  }
}

__global__ __launch_bounds__(256) void pair_kernel(
    float* __restrict__ ws) {
  __shared__ float redm[16], reds[16];
  if (blockIdx.z == 0) {
    // est1 (longer blocks) dispatched first; J=3, 256 j-tiles
    pair_body<HP1c, H1c, 3, true>(
        ws + HX1_OFF, ws + HYB1_OFF, ws + W2P_OFF + HP1c, ws + UHP_OFF + 1536,
        ws + PMAX_OFF + 3072, ws + PSUM_OFF + 3072, ws + DIAG_OFF + NROW,
        redm, reds);
  } else {
    if (blockIdx.x >= 192) return;   // est0 uses 192 of 256 x-slots
    pair_body<H0c, H0c, 4, false>(
        ws + HX0_OFF, ws + HYB0_OFF, ws + W2P_OFF, ws + UHP_OFF,
        ws + PMAX_OFF, ws + PSUM_OFF, ws + DIAG_OFF,
        redm, reds);
  }
}

// ---------------------------------------------------------------------------
// final: merge 3 i-quarter partials -> lse per row; sum (s_diag - lse).
// ---------------------------------------------------------------------------
__global__ __launch_bounds__(1024) void final_kernel(
    const float* __restrict__ ws, float* __restrict__ out) {
  __shared__ float red[1024];
  const int t = threadIdx.x;
  float val = 0.f;
  if (t < NROW) {
    #pragma unroll
    for (int est = 0; est < 2; ++est) {
      const float* pm = ws + PMAX_OFF + est * 3072 + t * 4;
      const float* ps = ws + PSUM_OFF + est * 3072 + t * 4;
      float M = fmaxf(fmaxf(pm[0], pm[1]), pm[2]);
      float S = ps[0] * __expf(pm[0] - M) + ps[1] * __expf(pm[1] - M) +
                ps[2] * __expf(pm[2] - M);
      float lse = M + logf(S);
      val += ws[DIAG_OFF + est * NROW + t] - lse;
    }
  }
  red[t] = val;
  __syncthreads();
  for (int sdown = 512; sdown > 0; sdown >>= 1) {
    if (t < sdown) red[t] += red[t + sdown];
    __syncthreads();
  }
  if (t == 0) out[0] = red[0] * (1.0f / (float)NROW) + 2.0f * logf((float)NROW);
}

// ---------------------------------------------------------------------------
extern "C" void kernel_launch(void* const* d_in, const int* in_sizes, int n_in,
                              void* d_out, int out_size, void* d_ws, size_t ws_size,
                              hipStream_t stream) {
  const float* s0   = (const float*)d_in[0];
  const float* s1   = (const float*)d_in[1];
  const float* s2   = (const float*)d_in[2];
  const float* W1_0 = (const float*)d_in[3];
  const float* b1_0 = (const float*)d_in[4];
  const float* W2_0 = (const float*)d_in[5];
  const float* W1_1 = (const float*)d_in[7];
  const float* b1_1 = (const float*)d_in[8];
  const float* W2_1 = (const float*)d_in[9];
  float* ws  = (float*)d_ws;
  float* out = (float*)d_out;

  hipLaunchKernelGGL(prep_kernel, dim3(48, 6), dim3(64, 4), 0, stream,
                     s0, s1, s2, W1_0, b1_0, W2_0, W1_1, b1_1, W2_1, ws);
  hipLaunchKernelGGL(pair_kernel, dim3(256, 3, 2), dim3(256), 0, stream, ws);
  hipLaunchKernelGGL(final_kernel, dim3(1), dim3(1024), 0, stream, ws, out);
}